// Round 11
// baseline (253.551 us; speedup 1.0000x reference)
//
#include <hip/hip_runtime.h>
#include <math.h>

#define TLEN 512
#define NB   1024
#define HSTR 80                 // h buf row stride (f16): 40 dwords -> <=2-way
#define HLAY (4 * HSTR)
#define XCH  64                 // timesteps per x chunk
#define XBSTR (XCH * 32 + 16)   // per-batch chunk stride (f16)
#define XHALF (4 * XBSTR)       // one chunk buffer (4 batches)

#define NLOG2E  (-1.44269504f)  // -log2(e): sigmoid gates
#define N2LOG2E (-2.88539008f)  // -2log2(e): tanh gate / tanh(c)

typedef _Float16 f16;
typedef f16   f16x4 __attribute__((ext_vector_type(4)));
typedef f16   f16x8 __attribute__((ext_vector_type(8)));
typedef float f32x4 __attribute__((ext_vector_type(4)));

__device__ __forceinline__ float ex2(float x) {
#if __has_builtin(__builtin_amdgcn_exp2f)
    return __builtin_amdgcn_exp2f(x);
#else
    return exp2f(x);
#endif
}
__device__ __forceinline__ float rcp_(float x) { return __builtin_amdgcn_rcpf(x); }
__device__ __forceinline__ float sel4(f32x4 v, int g) {
    float a = (g & 1) ? v[1] : v[0];
    float b = (g & 1) ? v[3] : v[2];
    return (g & 2) ? b : a;
}

// 256 blocks x 512 threads. Waves 0-3 = layer 0, waves 4-7 = layer 1.
// ROLE-STAGGERED half-phases (2 barriers/step): while L0 runs ds_read+MFMA,
// L1 runs act+write (and vice versa) -> MFMA pipe and VALU overlap across roles
// instead of serializing. L1's accumulators carry across the barrier: its gates
// for step t are MFMA'd in half2 of phase t+1 and activated in half1 of t+2.
// Broadcast B-reads; each lane owns ONE (hidden,batch) cell in registers.
__global__ __launch_bounds__(512, 1) void lstm_fused(
    const float* __restrict__ x,
    const float* __restrict__ Wih0, const float* __restrict__ Whh0,
    const float* __restrict__ bih0, const float* __restrict__ bhh0,
    const float* __restrict__ Wih1, const float* __restrict__ Whh1,
    const float* __restrict__ bih1, const float* __restrict__ bhh1,
    const float* __restrict__ fc1w, const float* __restrict__ fc1b,
    const float* __restrict__ fc2w, const float* __restrict__ fc2b,
    float* __restrict__ out)
{
    __shared__ __align__(16) f16 x_lds[2 * XHALF];    // ~33 KB
    __shared__ __align__(16) f16 h1buf[2 * HLAY];
    __shared__ __align__(16) f16 h2buf[2 * HLAY];
    __shared__ float zbuf[4][33];

    const int tid   = threadIdx.x;
    const int lane  = tid & 63;
    const int w     = tid >> 6;          // 0..7
    const int wg    = w & 3;             // hidden group within layer
    const bool isL0 = (w < 4);
    const int bc    = lane & 15;         // MFMA col / A-row-in-tile
    const int lq    = lane >> 4;         // k-octet / D-row quad
    const int G     = bc >> 2;           // copy-group -> acc reg this lane consumes
    const int b_own = bc & 3;            // batch this lane's column carries
    const int bg0   = blockIdx.x * 4;

    // ---- one-time: pre-scaled A-fragments + bias C-init vectors ----
    const float wsc[4] = {NLOG2E, NLOG2E, N2LOG2E, NLOG2E};
    f16x8 A[4][4];
    f32x4 cb[4];
    #pragma unroll
    for (int g = 0; g < 4; ++g) {
        const int gr = g * 64 + 16 * wg + bc;
        #pragma unroll
        for (int s = 0; s < 4; ++s) {
            #pragma unroll
            for (int i = 0; i < 8; ++i) {
                int k = 32 * s + lq * 8 + i;
                float v = 0.0f;
                if (isL0) {
                    if (s < 3) v = (k < 32) ? Wih0[gr * 32 + k] : Whh0[gr * 64 + (k - 32)];
                } else {
                    v = (k < 64) ? Wih1[gr * 64 + k] : Whh1[gr * 64 + (k - 64)];
                }
                A[g][s][i] = (f16)(v * wsc[g]);
            }
        }
        #pragma unroll
        for (int r = 0; r < 4; ++r) {
            const int gd = g * 64 + 16 * wg + 4 * lq + r;
            float bb = isL0 ? (bih0[gd] + bhh0[gd]) : (bih1[gd] + bhh1[gd]);
            cb[g][r] = bb * wsc[g];
        }
    }

    // ---- zero h LDS ----
    for (int i = tid; i < 2 * HLAY; i += 512) { h1buf[i] = (f16)0; h2buf[i] = (f16)0; }

    // ---- chunk refills ----
    // full-block version (pre-loop, chunk 0): 512 threads x 4 float4
    const int rf_b   = tid >> 7;
    const int rf_rem = tid & 127;
#define REFILL512(ch)                                                         \
    {                                                                         \
        f16* dst = x_lds + ((ch) & 1) * XHALF + rf_b * XBSTR;                 \
        const float4* src = (const float4*)(x +                               \
            ((long)(bg0 + rf_b) * TLEN + (ch) * XCH) * 32);                   \
        _Pragma("unroll")                                                     \
        for (int j = 0; j < 4; ++j) {                                         \
            float4 v = src[rf_rem + 128 * j];                                 \
            f16x4 hv;                                                         \
            hv[0]=(f16)v.x; hv[1]=(f16)v.y; hv[2]=(f16)v.z; hv[3]=(f16)v.w;   \
            *(f16x4*)(dst + (rf_rem + 128 * j) * 4) = hv;                     \
        }                                                                     \
    }
    // L1-waves-only version (in-loop): 256 threads x 8 float4
#define REFILL256(ch)                                                         \
    {                                                                         \
        f16* dst = x_lds + ((ch) & 1) * XHALF + wg * XBSTR;                   \
        const float4* src = (const float4*)(x +                               \
            ((long)(bg0 + wg) * TLEN + (ch) * XCH) * 32);                     \
        _Pragma("unroll")                                                     \
        for (int j = 0; j < 8; ++j) {                                         \
            float4 v = src[lane + 64 * j];                                    \
            f16x4 hv;                                                         \
            hv[0]=(f16)v.x; hv[1]=(f16)v.y; hv[2]=(f16)v.z; hv[3]=(f16)v.w;   \
            *(f16x4*)(dst + (lane + 64 * j) * 4) = hv;                        \
        }                                                                     \
    }

    REFILL512(0)                    // chunk 0 -> parity 0
    __syncthreads();

    const int bch = b_own * HSTR + lq * 8;                 // broadcast h B-frag offset
    const int bxx = b_own * XBSTR + lq * 8;                // x B-frag offset
    const int hwr = b_own * HSTR + 16 * wg + 4 * lq + G;   // h write

    float cst = 0.0f;
    f32x4 a0 = {0.f,0.f,0.f,0.f}, a1 = a0, a2 = a0, a3 = a0;

// L0 gate MFMA for step itv (parity P = itv&1): x[itv] + h1[P^1] -> a0..a3
#define L0_MFMA(P, itv)                                                       \
    {                                                                         \
        f16x8 b0 = *(const f16x8*)(x_lds + (((itv) >> 6) & 1) * XHALF +       \
                                   ((itv) & 63) * 32 + bxx);                  \
        f16x8 b1 = *(const f16x8*)(h1buf + ((P)^1) * HLAY + bch);             \
        f16x8 b2 = *(const f16x8*)(h1buf + ((P)^1) * HLAY + bch + 32);        \
        __builtin_amdgcn_s_setprio(1);                                        \
        a0 = __builtin_amdgcn_mfma_f32_16x16x32_f16(A[0][0], b0, cb[0], 0,0,0); \
        a1 = __builtin_amdgcn_mfma_f32_16x16x32_f16(A[1][0], b0, cb[1], 0,0,0); \
        a2 = __builtin_amdgcn_mfma_f32_16x16x32_f16(A[2][0], b0, cb[2], 0,0,0); \
        a3 = __builtin_amdgcn_mfma_f32_16x16x32_f16(A[3][0], b0, cb[3], 0,0,0); \
        a0 = __builtin_amdgcn_mfma_f32_16x16x32_f16(A[0][1], b1, a0, 0,0,0);  \
        a1 = __builtin_amdgcn_mfma_f32_16x16x32_f16(A[1][1], b1, a1, 0,0,0);  \
        a2 = __builtin_amdgcn_mfma_f32_16x16x32_f16(A[2][1], b1, a2, 0,0,0);  \
        a3 = __builtin_amdgcn_mfma_f32_16x16x32_f16(A[3][1], b1, a3, 0,0,0);  \
        a0 = __builtin_amdgcn_mfma_f32_16x16x32_f16(A[0][2], b2, a0, 0,0,0);  \
        a1 = __builtin_amdgcn_mfma_f32_16x16x32_f16(A[1][2], b2, a1, 0,0,0);  \
        a2 = __builtin_amdgcn_mfma_f32_16x16x32_f16(A[2][2], b2, a2, 0,0,0);  \
        a3 = __builtin_amdgcn_mfma_f32_16x16x32_f16(A[3][2], b2, a3, 0,0,0);  \
        __builtin_amdgcn_s_setprio(0);                                        \
    }

// L1 gate MFMA, phase ph (parity P = ph&1): h1[P^1] (=h1[ph-1]) + h2[P]
// (=h2[ph-2], written this phase's half1) -> a0..a3 for step t=ph-1.
#define L1_MFMA(P)                                                            \
    {                                                                         \
        f16x8 b0 = *(const f16x8*)(h1buf + ((P)^1) * HLAY + bch);             \
        f16x8 b1 = *(const f16x8*)(h1buf + ((P)^1) * HLAY + bch + 32);        \
        f16x8 b2 = *(const f16x8*)(h2buf + (P) * HLAY + bch);                 \
        f16x8 b3 = *(const f16x8*)(h2buf + (P) * HLAY + bch + 32);            \
        __builtin_amdgcn_s_setprio(1);                                        \
        a0 = __builtin_amdgcn_mfma_f32_16x16x32_f16(A[0][0], b0, cb[0], 0,0,0); \
        a1 = __builtin_amdgcn_mfma_f32_16x16x32_f16(A[1][0], b0, cb[1], 0,0,0); \
        a2 = __builtin_amdgcn_mfma_f32_16x16x32_f16(A[2][0], b0, cb[2], 0,0,0); \
        a3 = __builtin_amdgcn_mfma_f32_16x16x32_f16(A[3][0], b0, cb[3], 0,0,0); \
        a0 = __builtin_amdgcn_mfma_f32_16x16x32_f16(A[0][1], b1, a0, 0,0,0);  \
        a1 = __builtin_amdgcn_mfma_f32_16x16x32_f16(A[1][1], b1, a1, 0,0,0);  \
        a2 = __builtin_amdgcn_mfma_f32_16x16x32_f16(A[2][1], b1, a2, 0,0,0);  \
        a3 = __builtin_amdgcn_mfma_f32_16x16x32_f16(A[3][1], b1, a3, 0,0,0);  \
        a0 = __builtin_amdgcn_mfma_f32_16x16x32_f16(A[0][2], b2, a0, 0,0,0);  \
        a1 = __builtin_amdgcn_mfma_f32_16x16x32_f16(A[1][2], b2, a1, 0,0,0);  \
        a2 = __builtin_amdgcn_mfma_f32_16x16x32_f16(A[2][2], b2, a2, 0,0,0);  \
        a3 = __builtin_amdgcn_mfma_f32_16x16x32_f16(A[3][2], b2, a3, 0,0,0);  \
        a0 = __builtin_amdgcn_mfma_f32_16x16x32_f16(A[0][3], b3, a0, 0,0,0);  \
        a1 = __builtin_amdgcn_mfma_f32_16x16x32_f16(A[1][3], b3, a1, 0,0,0);  \
        a2 = __builtin_amdgcn_mfma_f32_16x16x32_f16(A[2][3], b3, a2, 0,0,0);  \
        a3 = __builtin_amdgcn_mfma_f32_16x16x32_f16(A[3][3], b3, a3, 0,0,0);  \
        __builtin_amdgcn_s_setprio(0);                                        \
    }

// activate a0..a3 and store this lane's h to HBUF parity P
#define ACT_STORE(HBUF, P)                                                    \
    {                                                                         \
        float pi = sel4(a0, G);                                               \
        float pf = sel4(a1, G);                                               \
        float pg = sel4(a2, G);                                               \
        float po = sel4(a3, G);                                               \
        float iv = rcp_(1.0f + ex2(pi));                                      \
        float fv = rcp_(1.0f + ex2(pf));                                      \
        float gv = fmaf(2.0f, rcp_(1.0f + ex2(pg)), -1.0f);                   \
        float ov = rcp_(1.0f + ex2(po));                                      \
        cst = fmaf(fv, cst, iv * gv);                                         \
        float tc = fmaf(2.0f, rcp_(1.0f + ex2(cst * N2LOG2E)), -1.0f);        \
        HBUF[(P) * HLAY + hwr] = (f16)(ov * tc);                              \
    }

    // ================= pipeline =================
    // peel ph=0
    if (isL0) { L0_MFMA(0, 0) } else { REFILL256(1) }
    __syncthreads();
    if (isL0) { ACT_STORE(h1buf, 0) }
    __syncthreads();
    // peel ph=1
    if (isL0) { L0_MFMA(1, 1) }
    __syncthreads();
    if (isL0) { ACT_STORE(h1buf, 1) } else { L1_MFMA(1) }
    __syncthreads();

    // main: ph = 2k, 2k+1 for k = 1..255  (ph 2..511)
    #pragma unroll 1
    for (int k = 1; k <= 255; ++k) {
        const int phe = 2 * k;
        // ---- even phase (P=0) ----
        if (isL0) { L0_MFMA(0, phe) }
        else {
            ACT_STORE(h2buf, 0)                    // h2[phe-2]
            if ((phe & 63) == 0 && phe <= 384) REFILL256((phe >> 6) + 1)
        }
        __syncthreads();
        if (isL0) { ACT_STORE(h1buf, 0) } else { L1_MFMA(0) }
        __syncthreads();
        // ---- odd phase (P=1) ----
        if (isL0) { L0_MFMA(1, phe + 1) } else { ACT_STORE(h2buf, 1) }
        __syncthreads();
        if (isL0) { ACT_STORE(h1buf, 1) } else { L1_MFMA(1) }
        __syncthreads();
    }

    // tail ph=512 (P=0): L1 act h2[510], then MFMA t=511
    if (!isL0) { ACT_STORE(h2buf, 0) }
    __syncthreads();
    if (!isL0) { L1_MFMA(0) }
    __syncthreads();
    // tail ph=513 (P=1): L1 act h2[511] -> parity 1
    if (!isL0) { ACT_STORE(h2buf, 1) }
    __syncthreads();

#undef L0_MFMA
#undef L1_MFMA
#undef ACT_STORE
#undef REFILL512
#undef REFILL256

    // ---- FC head: h2[511] is in parity 1 ----
    const f16* h2f = h2buf + HLAY;
    if (tid < 128) {
        int b = tid >> 5, m = tid & 31;
        float z = fc1b[m];
        #pragma unroll
        for (int j = 0; j < 64; ++j)
            z = fmaf(fc1w[m * 64 + j], (float)h2f[b * HSTR + j], z);
        zbuf[b][m] = fmaxf(z, 0.0f);
    }
    __syncthreads();
    if (tid < 8) {
        int b = tid >> 1, o = tid & 1;
        float s = fc2b[o];
        #pragma unroll
        for (int m = 0; m < 32; ++m)
            s = fmaf(fc2w[o * 32 + m], zbuf[b][m], s);
        out[(long)(bg0 + b) * 2 + o] = s;
    }
}

extern "C" void kernel_launch(void* const* d_in, const int* in_sizes, int n_in,
                              void* d_out, int out_size, void* d_ws, size_t ws_size,
                              hipStream_t stream) {
    const float* x    = (const float*)d_in[0];
    const float* Wih0 = (const float*)d_in[1];
    const float* Whh0 = (const float*)d_in[2];
    const float* bih0 = (const float*)d_in[3];
    const float* bhh0 = (const float*)d_in[4];
    const float* Wih1 = (const float*)d_in[5];
    const float* Whh1 = (const float*)d_in[6];
    const float* bih1 = (const float*)d_in[7];
    const float* bhh1 = (const float*)d_in[8];
    const float* fc1w = (const float*)d_in[9];
    const float* fc1b = (const float*)d_in[10];
    const float* fc2w = (const float*)d_in[11];
    const float* fc2b = (const float*)d_in[12];
    float* out = (float*)d_out;

    lstm_fused<<<dim3(NB / 4), dim3(512), 0, stream>>>(
        x, Wih0, Whh0, bih0, bhh0, Wih1, Whh1, bih1, bhh1,
        fc1w, fc1b, fc2w, fc2b, out);
}